// Round 1
// baseline (47.573 us; speedup 1.0000x reference)
//
#include <hip/hip_runtime.h>

// SimSiam loss, algebraically reduced:
//   loss = -0.5 * (sum_c S_p(c).S_z(c) - sum_i pn_i.zn_i) / npairs
// where S_p(c) = sum of normalized p rows with target c, npairs = sum_c n_c*(n_c-1)/2.
// O(n*d) instead of the reference's O(n^2*d) cosine matrix.

constexpr int D     = 128;   // row dim (fixed by reference)
constexpr int NCLS  = 512;   // n_classes (fixed by reference)
constexpr float EPS = 1e-8f; // cosine_similarity eps

// ---------------- K1: row norms -> scales, trace partials, class histogram ----
__global__ void k1_norms(const float* __restrict__ ps, const float* __restrict__ zs,
                         const int* __restrict__ targets,
                         float* __restrict__ scale_p, float* __restrict__ scale_z,
                         int* __restrict__ counts, float* __restrict__ diag, int n) {
    const int lane = threadIdx.x & 63;
    const int wib  = threadIdx.x >> 6;
    const int wpb  = blockDim.x >> 6;
    const int gwid = blockIdx.x * wpb + wib;
    const int nw   = gridDim.x * wpb;

    float diag_acc = 0.0f;
    for (int row = gwid; row < n; row += nw) {
        // d=128 -> one float2 per lane
        float2 p = reinterpret_cast<const float2*>(ps)[row * (D / 2) + lane];
        float2 z = reinterpret_cast<const float2*>(zs)[row * (D / 2) + lane];
        float ssp = p.x * p.x + p.y * p.y;
        float ssz = z.x * z.x + z.y * z.y;
        float pz  = p.x * z.x + p.y * z.y;
#pragma unroll
        for (int m = 32; m > 0; m >>= 1) {
            ssp += __shfl_xor(ssp, m, 64);
            ssz += __shfl_xor(ssz, m, 64);
            pz  += __shfl_xor(pz,  m, 64);
        }
        float sp = 1.0f / fmaxf(sqrtf(ssp), EPS);
        float sz = 1.0f / fmaxf(sqrtf(ssz), EPS);
        if (lane == 0) {
            scale_p[row] = sp;
            scale_z[row] = sz;
            diag_acc += pz * sp * sz;          // trace contribution
            atomicAdd(&counts[targets[row]], 1);
        }
    }
    __shared__ float sdiag[16];
    if (lane == 0) sdiag[wib] = diag_acc;
    __syncthreads();
    if (threadIdx.x == 0) {
        float s = 0.0f;
        for (int w = 0; w < wpb; ++w) s += sdiag[w];
        atomicAdd(diag, s);
    }
}

// ---------------- K2: exclusive scan of counts -> cursor; npairs --------------
__global__ void k2_scan(const int* __restrict__ counts, int* __restrict__ cursor,
                        int* __restrict__ npairs_out) {
    __shared__ int a[NCLS], b[NCLS];
    __shared__ int np;
    const int t = threadIdx.x;  // 512 threads
    int c = counts[t];
    a[t] = c;
    if (t == 0) np = 0;
    __syncthreads();
    int parity = 0;
    for (int off = 1; off < NCLS; off <<= 1) {
        int* src = parity ? b : a;
        int* dst = parity ? a : b;
        dst[t] = src[t] + (t >= off ? src[t - off] : 0);
        parity ^= 1;
        __syncthreads();
    }
    int* fin = parity ? b : a;      // inclusive scan
    cursor[t] = fin[t] - c;         // exclusive prefix -> scatter start
    atomicAdd(&np, c * (c - 1) / 2);
    __syncthreads();
    if (t == 0) npairs_out[0] = np;
}

// ---------------- K3: scatter row indices into per-class buckets --------------
__global__ void k3_scatter(const int* __restrict__ targets, int* __restrict__ cursor,
                           int* __restrict__ rowidx, int n) {
    int i = blockIdx.x * blockDim.x + threadIdx.x;
    if (i < n) {
        int pos = atomicAdd(&cursor[targets[i]], 1);
        rowidx[pos] = i;
    }
}

// ---------------- K4: one wave per class: S_p.S_z -----------------------------
__global__ void k4_classdot(const float* __restrict__ ps, const float* __restrict__ zs,
                            const float* __restrict__ scale_p, const float* __restrict__ scale_z,
                            const int* __restrict__ counts, const int* __restrict__ cursor,
                            const int* __restrict__ rowidx, float* __restrict__ csum) {
    const int lane = threadIdx.x & 63;
    const int wib  = threadIdx.x >> 6;
    const int wpb  = blockDim.x >> 6;
    const int c    = blockIdx.x * wpb + wib;

    float spx = 0, spy = 0, szx = 0, szy = 0;
    if (c < NCLS) {
        int cnt   = counts[c];
        int start = cursor[c] - cnt;   // cursor was advanced by cnt in K3
        for (int k = 0; k < cnt; ++k) {
            int row  = rowidx[start + k];
            float2 p = reinterpret_cast<const float2*>(ps)[row * (D / 2) + lane];
            float2 z = reinterpret_cast<const float2*>(zs)[row * (D / 2) + lane];
            float sp = scale_p[row], sz = scale_z[row];
            spx += p.x * sp; spy += p.y * sp;
            szx += z.x * sz; szy += z.y * sz;
        }
    }
    float term = spx * szx + spy * szy;
#pragma unroll
    for (int m = 32; m > 0; m >>= 1) term += __shfl_xor(term, m, 64);

    __shared__ float st[16];
    if (lane == 0) st[wib] = term;
    __syncthreads();
    if (threadIdx.x == 0) {
        float s = 0.0f;
        for (int w = 0; w < wpb; ++w) s += st[w];
        atomicAdd(csum, s);
    }
}

// ---------------- K5: finalize -------------------------------------------------
__global__ void k5_final(const float* __restrict__ diag, const float* __restrict__ csum,
                         const int* __restrict__ npairs, float* __restrict__ out) {
    if (threadIdx.x == 0 && blockIdx.x == 0) {
        float np = (float)(npairs[0] > 0 ? npairs[0] : 1);
        out[0] = -0.5f * (csum[0] - diag[0]) / np;
    }
}

extern "C" void kernel_launch(void* const* d_in, const int* in_sizes, int n_in,
                              void* d_out, int out_size, void* d_ws, size_t ws_size,
                              hipStream_t stream) {
    const float* ps      = (const float*)d_in[0];
    const float* zs      = (const float*)d_in[1];
    const int*   targets = (const int*)d_in[2];
    float*       out     = (float*)d_out;
    const int n = in_sizes[2];   // 8192

    // workspace layout (floats): scale_p[n], scale_z[n], then ints/accumulators
    float* ws      = (float*)d_ws;
    float* scale_p = ws;
    float* scale_z = ws + n;
    int*   counts  = (int*)(ws + 2 * n);          // [NCLS]   zeroed each call
    float* diag    = (float*)(counts + NCLS);     // [1]      zeroed each call
    float* csum    = diag + 1;                    // [1]      zeroed each call
    int*   npairs  = (int*)(csum + 1);            // [1]      written by K2
    int*   cursor  = npairs + 1;                  // [NCLS]   written by K2
    int*   rowidx  = cursor + NCLS;               // [n]      written by K3

    // zero counts + diag + csum (contiguous)
    hipMemsetAsync(counts, 0, (NCLS + 2) * sizeof(int), stream);

    k1_norms<<<128, 256, 0, stream>>>(ps, zs, targets, scale_p, scale_z, counts, diag, n);
    k2_scan<<<1, NCLS, 0, stream>>>(counts, cursor, npairs);
    k3_scatter<<<(n + 255) / 256, 256, 0, stream>>>(targets, cursor, rowidx, n);
    k4_classdot<<<NCLS / 4, 256, 0, stream>>>(ps, zs, scale_p, scale_z, counts, cursor, rowidx, csum);
    k5_final<<<1, 1, 0, stream>>>(diag, csum, npairs, out);
}

// Round 2
// 29.608 us; speedup vs baseline: 1.6068x; 1.6068x over previous
//
#include <hip/hip_runtime.h>

// SimSiam loss, algebraically reduced:
//   loss = -0.5 * (sum_c S_p(c).S_z(c) - sum_i pn_i.zn_i) / npairs
//   npairs = sum_c n_c*(n_c-1)/2
// Two dispatches, no atomics, no memset, fully deterministic:
//   K_main : one wave per class; scan targets via int4+ballot, gather rows,
//            inline norm reduction, register accumulation of S_p,S_z,diag,cnt
//   K_final: 1-block LDS tree reduction of 512 per-class records -> loss

constexpr int   D    = 128;    // row dim (fixed by reference)
constexpr int   NCLS = 512;    // n_classes (fixed by reference)
constexpr float EPS  = 1e-8f;  // cosine_similarity eps

__device__ __forceinline__ void process_row(
    const float2* __restrict__ p2, const float2* __restrict__ z2,
    int row, int lane,
    float& spx, float& spy, float& szx, float& szy, float& dacc) {
    float2 p = p2[row * (D / 2) + lane];
    float2 z = z2[row * (D / 2) + lane];
    float ssp = p.x * p.x + p.y * p.y;
    float ssz = z.x * z.x + z.y * z.y;
    float spz = p.x * z.x + p.y * z.y;
#pragma unroll
    for (int m = 1; m < 64; m <<= 1) {
        ssp += __shfl_xor(ssp, m, 64);
        ssz += __shfl_xor(ssz, m, 64);
        spz += __shfl_xor(spz, m, 64);
    }
    // all lanes now hold identical ssp/ssz/spz (butterfly broadcast)
    float sp = 1.0f / fmaxf(sqrtf(ssp), EPS);
    float sz = 1.0f / fmaxf(sqrtf(ssz), EPS);
    spx += p.x * sp;  spy += p.y * sp;
    szx += z.x * sz;  szy += z.y * sz;
    dacc += spz * sp * sz;   // identical on all lanes; written once by lane 0
}

// ---------------- K_main: one wave per class ---------------------------------
__global__ __launch_bounds__(256) void simsiam_main(
    const float* __restrict__ ps, const float* __restrict__ zs,
    const int* __restrict__ targets, float4* __restrict__ res, int n) {
    const int lane = threadIdx.x & 63;
    const int c    = blockIdx.x * (blockDim.x >> 6) + (threadIdx.x >> 6);
    if (c >= NCLS) return;

    const float2* p2 = reinterpret_cast<const float2*>(ps);
    const float2* z2 = reinterpret_cast<const float2*>(zs);

    float spx = 0.f, spy = 0.f, szx = 0.f, szy = 0.f, dacc = 0.f;
    int cnt = 0;

    // 256 targets per iteration: one int4 load per lane, 4 ballots
    int base = 0;
    for (; base + 256 <= n; base += 256) {
        int4 t = reinterpret_cast<const int4*>(targets + base)[lane];
        unsigned long long b0 = __ballot(t.x == c);
        unsigned long long b1 = __ballot(t.y == c);
        unsigned long long b2 = __ballot(t.z == c);
        unsigned long long b3 = __ballot(t.w == c);
        cnt += __popcll(b0) + __popcll(b1) + __popcll(b2) + __popcll(b3);
        unsigned long long bms[4] = {b0, b1, b2, b3};
#pragma unroll
        for (int k = 0; k < 4; ++k) {
            unsigned long long bm = bms[k];
            while (bm) {                      // wave-uniform: bm identical on all lanes
                int l = __ffsll(bm) - 1;
                bm &= bm - 1;
                process_row(p2, z2, base + 4 * l + k, lane, spx, spy, szx, szy, dacc);
            }
        }
    }
    // tail (not taken for n=8192)
    for (int i = base; i < n; i += 64) {
        int idx = i + lane;
        int t   = (idx < n) ? targets[idx] : -1;
        unsigned long long bm = __ballot(t == c);
        cnt += __popcll(bm);
        while (bm) {
            int l = __ffsll(bm) - 1;
            bm &= bm - 1;
            process_row(p2, z2, i + l, lane, spx, spy, szx, szy, dacc);
        }
    }

    float term = spx * szx + spy * szy;
#pragma unroll
    for (int m = 1; m < 64; m <<= 1) term += __shfl_xor(term, m, 64);

    if (lane == 0) res[c] = make_float4(term, dacc, (float)cnt, 0.f);
}

// ---------------- K_final: reduce 512 class records --------------------------
__global__ __launch_bounds__(NCLS) void simsiam_final(
    const float4* __restrict__ res, float* __restrict__ out) {
    __shared__ float sv[NCLS], sd[NCLS], sn[NCLS];
    const int t = threadIdx.x;
    float4 r = res[t];
    sv[t] = r.x;
    sd[t] = r.y;
    sn[t] = r.z * (r.z - 1.0f) * 0.5f;   // n_c*(n_c-1)/2, exact in f32
    __syncthreads();
    for (int off = NCLS / 2; off > 0; off >>= 1) {
        if (t < off) {
            sv[t] += sv[t + off];
            sd[t] += sd[t + off];
            sn[t] += sn[t + off];
        }
        __syncthreads();
    }
    if (t == 0) {
        float np = fmaxf(sn[0], 1.0f);
        out[0] = -0.5f * (sv[0] - sd[0]) / np;
    }
}

extern "C" void kernel_launch(void* const* d_in, const int* in_sizes, int n_in,
                              void* d_out, int out_size, void* d_ws, size_t ws_size,
                              hipStream_t stream) {
    const float* ps      = (const float*)d_in[0];
    const float* zs      = (const float*)d_in[1];
    const int*   targets = (const int*)d_in[2];
    float*       out     = (float*)d_out;
    const int n = in_sizes[2];   // 8192

    float4* res = (float4*)d_ws;  // [NCLS], written unconditionally each call

    simsiam_main<<<NCLS / 4, 256, 0, stream>>>(ps, zs, targets, res, n);
    simsiam_final<<<1, NCLS, 0, stream>>>(res, out);
}

// Round 3
// 14.413 us; speedup vs baseline: 3.3006x; 2.0542x over previous
//
#include <hip/hip_runtime.h>

// SimSiam loss, algebraically reduced:
//   loss = -0.5 * (sum_c S_p(c).S_z(c) - sum_i pn_i.zn_i) / npairs
//   npairs = sum_c n_c*(n_c-1)/2
// Dispatch 1: one block (8 waves) per class; each wave scans 1/8 of targets
//             (int4+ballot), computes norms inline for its matched rows
//             (each row belongs to exactly one class -> norms computed once),
//             accumulates S_p,S_z fragments + diag + cnt; LDS cross-wave reduce.
// Dispatch 2: 1-block reduction of 512 class records -> scalar loss.
// No atomics, no memset, deterministic accumulation order.

constexpr int   D    = 128;    // row dim (fixed by reference)
constexpr int   NCLS = 512;    // n_classes (fixed by reference)
constexpr float EPS  = 1e-8f;  // cosine_similarity eps

__device__ __forceinline__ void process_row(
    const float2* __restrict__ p2, const float2* __restrict__ z2,
    int row, int lane,
    float& spx, float& spy, float& szx, float& szy, float& dacc) {
    float2 p = p2[row * (D / 2) + lane];
    float2 z = z2[row * (D / 2) + lane];
    float ssp = p.x * p.x + p.y * p.y;
    float ssz = z.x * z.x + z.y * z.y;
    float spz = p.x * z.x + p.y * z.y;
#pragma unroll
    for (int m = 1; m < 64; m <<= 1) {
        ssp += __shfl_xor(ssp, m, 64);
        ssz += __shfl_xor(ssz, m, 64);
        spz += __shfl_xor(spz, m, 64);
    }
    // all lanes hold identical ssp/ssz/spz after butterfly
    float sp = 1.0f / fmaxf(sqrtf(ssp), EPS);
    float sz = 1.0f / fmaxf(sqrtf(ssz), EPS);
    spx += p.x * sp;  spy += p.y * sp;
    szx += z.x * sz;  szy += z.y * sz;
    dacc += spz * sp * sz;   // identical on all lanes; consumed from wave scalar
}

// ---------------- K1: one block per class, 8 waves scan disjoint ranges ------
__global__ __launch_bounds__(512) void simsiam_class(
    const float* __restrict__ ps, const float* __restrict__ zs,
    const int* __restrict__ targets, float4* __restrict__ res, int n) {
    const int lane = threadIdx.x & 63;
    const int wave = threadIdx.x >> 6;   // 0..7
    const int c    = blockIdx.x;         // class id

    const float2* p2 = reinterpret_cast<const float2*>(ps);
    const float2* z2 = reinterpret_cast<const float2*>(zs);

    // per-wave target range, multiple of 256 so the int4 loop has no interior tail
    const int stride = (((n + 7) / 8 + 255) / 256) * 256;
    const int lo = wave * stride;
    const int hi = min(n, lo + stride);

    float spx = 0.f, spy = 0.f, szx = 0.f, szy = 0.f, dacc = 0.f;
    int cnt = 0;

    int base = lo;
    for (; base + 256 <= hi; base += 256) {
        int4 t = reinterpret_cast<const int4*>(targets + base)[lane];
        unsigned long long b0 = __ballot(t.x == c);
        unsigned long long b1 = __ballot(t.y == c);
        unsigned long long b2 = __ballot(t.z == c);
        unsigned long long b3 = __ballot(t.w == c);
        cnt += __popcll(b0) + __popcll(b1) + __popcll(b2) + __popcll(b3);
        unsigned long long bms[4] = {b0, b1, b2, b3};
#pragma unroll
        for (int k = 0; k < 4; ++k) {
            unsigned long long bm = bms[k];
            while (bm) {                 // wave-uniform mask
                int l = __ffsll(bm) - 1;
                bm &= bm - 1;
                process_row(p2, z2, base + 4 * l + k, lane, spx, spy, szx, szy, dacc);
            }
        }
    }
    for (int i = base; i < hi; i += 64) {   // generic tail (not taken for n=8192)
        int idx = i + lane;
        int t   = (idx < hi) ? targets[idx] : -1;
        unsigned long long bm = __ballot(t == c);
        cnt += __popcll(bm);
        while (bm) {
            int l = __ffsll(bm) - 1;
            bm &= bm - 1;
            process_row(p2, z2, i + l, lane, spx, spy, szx, szy, dacc);
        }
    }

    // cross-wave reduction of S fragments (deterministic order)
    __shared__ float4 sAcc[8][64];      // 8 KB
    __shared__ float  sD[8];
    __shared__ int    sC[8];
    sAcc[wave][lane] = make_float4(spx, spy, szx, szy);
    if (lane == 0) { sD[wave] = dacc; sC[wave] = cnt; }
    __syncthreads();

    if (wave == 0) {
        float4 a = sAcc[0][lane];
#pragma unroll
        for (int w = 1; w < 8; ++w) {
            float4 b = sAcc[w][lane];
            a.x += b.x; a.y += b.y; a.z += b.z; a.w += b.w;
        }
        float term = a.x * a.z + a.y * a.w;   // S_p . S_z (this lane's fragment)
#pragma unroll
        for (int m = 1; m < 64; m <<= 1) term += __shfl_xor(term, m, 64);

        float dtot = 0.f; int ctot = 0;
#pragma unroll
        for (int w = 0; w < 8; ++w) { dtot += sD[w]; ctot += sC[w]; }

        if (lane == 0) res[c] = make_float4(term, dtot, (float)ctot, 0.f);
    }
}

// ---------------- K2: reduce 512 class records -------------------------------
__global__ __launch_bounds__(NCLS) void simsiam_final(
    const float4* __restrict__ res, float* __restrict__ out) {
    __shared__ float sv[NCLS], sd[NCLS], sn[NCLS];
    const int t = threadIdx.x;
    float4 r = res[t];
    sv[t] = r.x;
    sd[t] = r.y;
    sn[t] = r.z * (r.z - 1.0f) * 0.5f;   // n_c*(n_c-1)/2, exact in f32
    __syncthreads();
    for (int off = NCLS / 2; off > 0; off >>= 1) {
        if (t < off) {
            sv[t] += sv[t + off];
            sd[t] += sd[t + off];
            sn[t] += sn[t + off];
        }
        __syncthreads();
    }
    if (t == 0) {
        float np = fmaxf(sn[0], 1.0f);
        out[0] = -0.5f * (sv[0] - sd[0]) / np;
    }
}

extern "C" void kernel_launch(void* const* d_in, const int* in_sizes, int n_in,
                              void* d_out, int out_size, void* d_ws, size_t ws_size,
                              hipStream_t stream) {
    const float* ps      = (const float*)d_in[0];
    const float* zs      = (const float*)d_in[1];
    const int*   targets = (const int*)d_in[2];
    float*       out     = (float*)d_out;
    const int n = in_sizes[2];   // 8192

    float4* res = (float4*)d_ws;  // [NCLS], written unconditionally each call

    simsiam_class<<<NCLS, 512, 0, stream>>>(ps, zs, targets, res, n);
    simsiam_final<<<1, NCLS, 0, stream>>>(res, out);
}